// Round 4
// baseline (293.763 us; speedup 1.0000x reference)
//
#include <hip/hip_runtime.h>
#include <hip/hip_bf16.h>

typedef __bf16 bf16;
typedef __bf16 bf16x4 __attribute__((ext_vector_type(4)));
typedef __bf16 bf16x8 __attribute__((ext_vector_type(8)));
typedef float  f32x4  __attribute__((ext_vector_type(4)));

#define NEG_BIG (-1e30f)
#define LOG2E 1.44269504088896340736f

#define AS1(p) ((const __attribute__((address_space(1))) void*)(p))
#define AS3(p) ((__attribute__((address_space(3))) void*)(p))

// async global->LDS, 16B/lane; dest = wave-uniform base + lane*16 (m104/m108)
__device__ __forceinline__ void stage16(const void* g, void* lds_uniform_base) {
    __builtin_amdgcn_global_load_lds(AS1(g), AS3(lds_uniform_base), 16, 0, 0);
}

__device__ __forceinline__ bf16x8 cvt8(const float* __restrict__ p) {
    bf16x8 r;
#pragma unroll
    for (int i = 0; i < 8; ++i) r[i] = (bf16)p[i];
    return r;
}

// ---- DPP butterfly reduce over 16 consecutive lanes (pure VALU, no LDS) ----
template <int CTRL>
__device__ __forceinline__ float dpp_max_step(float x) {
    int v = __builtin_bit_cast(int, x);
    int s = __builtin_amdgcn_update_dpp(v, v, CTRL, 0xF, 0xF, true);
    return fmaxf(x, __builtin_bit_cast(float, s));
}
template <int CTRL>
__device__ __forceinline__ float dpp_add_step(float x) {
    int v = __builtin_bit_cast(int, x);
    int s = __builtin_amdgcn_update_dpp(v, v, CTRL, 0xF, 0xF, true);
    return x + __builtin_bit_cast(float, s);
}
__device__ __forceinline__ float red16_max(float x) {
    x = dpp_max_step<0xB1>(x);
    x = dpp_max_step<0x4E>(x);
    x = dpp_max_step<0x141>(x);
    x = dpp_max_step<0x140>(x);
    return x;
}
__device__ __forceinline__ float red16_sum(float x) {
    x = dpp_add_step<0xB1>(x);
    x = dpp_add_step<0x4E>(x);
    x = dpp_add_step<0x141>(x);
    x = dpp_add_step<0x140>(x);
    return x;
}

#if __has_builtin(__builtin_amdgcn_exp2f)
#define EXP2F(x) __builtin_amdgcn_exp2f(x)
#else
#define EXP2F(x) exp2f(x)
#endif

// ---------------------------------------------------------------------------
// f32->bf16: x -> xb (ws), Wq/Wk/Wv -> wb (d_out scratch). (R7-proven.)
// ---------------------------------------------------------------------------
__global__ __launch_bounds__(256) void conv_all(
    const float* __restrict__ x,  const float* __restrict__ wq,
    const float* __restrict__ wk, const float* __restrict__ wv,
    bf16* __restrict__ xb, bf16* __restrict__ wb)
{
    const int blk = blockIdx.x;
    const float* src; bf16* dst; size_t off;
    if (blk < 2048)      { src = x;  dst = xb;           off = (size_t)blk * 2048; }
    else if (blk < 2560) { src = wq; dst = wb;           off = (size_t)(blk - 2048) * 2048; }
    else if (blk < 3072) { src = wk; dst = wb + 1048576; off = (size_t)(blk - 2560) * 2048; }
    else                 { src = wv; dst = wb + 2097152; off = (size_t)(blk - 3072) * 2048; }
    const size_t i = off + (size_t)threadIdx.x * 8;
    *(bf16x8*)(dst + i) = cvt8(src + i);
}

// ---------------------------------------------------------------------------
// Fused QKV projection, all-bf16 (R7-proven core). y = xb @ Wb.T + b.
// Q is scaled by 0.125*log2e (exp2-domain softmax). V is written TRANSPOSED:
// V^T[bh][64][2048] so attn reads it directly as the PV B-operand.
// ---------------------------------------------------------------------------
__global__ __launch_bounds__(256) void qkv_gemm(
    const bf16* __restrict__ Xb, const bf16* __restrict__ Wb,
    const float* __restrict__ bq, const float* __restrict__ bk, const float* __restrict__ bv,
    bf16* __restrict__ qo, bf16* __restrict__ ko, bf16* __restrict__ vo)
{
    __shared__ alignas(16) bf16 As[128 * 32];
    __shared__ alignas(16) bf16 Bs[128 * 32];

    const int t    = threadIdx.x;
    const int lane = t & 63, w = t >> 6;
    const int quad = lane >> 4, col = lane & 15;
    const int nt = blockIdx.x;            // 0..23
    const int mt = blockIdx.y;            // 0..31
    const int region = nt >> 3;           // 0=q 1=k 2=v
    const int n0 = (nt & 7) * 128;
    const int m0 = mt * 128;
    const int K  = 1024;

    const bf16*  W    = Wb + (size_t)region * 1048576;
    const float* bias = region == 0 ? bq : (region == 1 ? bk : bv);

    const int wm = (w >> 1) * 64, wn = (w & 1) * 64;
    f32x4 acc[4][4] = {};

    for (int k0 = 0; k0 < K; k0 += 32) {
        __syncthreads();
#pragma unroll
        for (int i = 0; i < 2; ++i) {
            int c = i * 256 + t;
            stage16(Xb + (size_t)(m0 + (c >> 2)) * K + k0 + (c & 3) * 8,
                    As + (i * 256 + w * 64) * 8);
        }
#pragma unroll
        for (int i = 0; i < 2; ++i) {
            int c = i * 256 + t;
            stage16(W + (size_t)(n0 + (c >> 2)) * K + k0 + (c & 3) * 8,
                    Bs + (i * 256 + w * 64) * 8);
        }
        __syncthreads();

        bf16x8 a[4], b[4];
#pragma unroll
        for (int i = 0; i < 4; ++i)
            a[i] = *(const bf16x8*)(As + (wm + i * 16 + col) * 32 + quad * 8);
#pragma unroll
        for (int j = 0; j < 4; ++j)
            b[j] = *(const bf16x8*)(Bs + (wn + j * 16 + col) * 32 + quad * 8);
#pragma unroll
        for (int i = 0; i < 4; ++i)
#pragma unroll
            for (int j = 0; j < 4; ++j)
                acc[i][j] = __builtin_amdgcn_mfma_f32_16x16x32_bf16(a[i], b[j], acc[i][j], 0, 0, 0);
    }

    if (region == 2) {
        // V^T epilogue: rows d = n&63, cols s (contiguous in r) -> packed 8B stores
#pragma unroll
        for (int i = 0; i < 4; ++i) {
            const int mbase = m0 + wm + i * 16 + quad * 4;
            const int b_ = mbase >> 11, s = mbase & 2047;
#pragma unroll
            for (int j = 0; j < 4; ++j) {
                const int n = n0 + wn + j * 16 + col;
                const float bb = bias[n];
                const int h = n >> 6, d = n & 63;
                bf16x4 pk;
#pragma unroll
                for (int r = 0; r < 4; ++r) pk[r] = (bf16)(acc[i][j][r] + bb);
                *(bf16x4*)(vo + ((size_t)(b_ * 16 + h) * 64 + d) * 2048 + s) = pk;
            }
        }
    } else {
        bf16* out = region == 0 ? qo : ko;
        const float scale = region == 0 ? (0.125f * LOG2E) : 1.0f;
#pragma unroll
        for (int i = 0; i < 4; ++i) {
            const int mbase = m0 + wm + i * 16 + quad * 4;
#pragma unroll
            for (int j = 0; j < 4; ++j) {
                const int n = n0 + wn + j * 16 + col;
                const float bb = bias[n];
                const int h = n >> 6, d = n & 63;
#pragma unroll
                for (int r = 0; r < 4; ++r) {
                    const int m  = mbase + r;
                    const int b_ = m >> 11, s = m & 2047;
                    out[(((size_t)(b_ * 16 + h)) * 2048 + s) * 64 + d] =
                        (bf16)((acc[i][j][r] + bb) * scale);
                }
            }
        }
    }
}

// ---------------------------------------------------------------------------
// Flash attention — BARRIER-FREE. 256 equal-work blocks x 512 threads (R3
// grid), but K and V^T are read DIRECTLY from global (L1/L2-resident: 16KB
// K-tile + 16KB V-tile = L1 size; 8 waves reuse each tile -> ~7/8 L1 hits;
// both patterns are fully 64B-line-coalesced). DS pipe now carries ONLY the
// P roundtrip; K/V ride the previously-idle TA/L1 pipe in parallel. No LDS
// staging -> no double buffer -> ZERO __syncthreads: waves fully decoupled,
// V-loads hoist under softmax VALU automatically.
// LDS = P only: 8 waves x 16x136 bf16 = 34816 B.
// ---------------------------------------------------------------------------
__global__ __launch_bounds__(512, 2) void attn_kernel(
    const bf16* __restrict__ Q, const bf16* __restrict__ Kg,
    const bf16* __restrict__ Vt, bf16* __restrict__ O)
{
    const int t    = threadIdx.x;
    const int lane = t & 63, w = t >> 6;      // w = 0..7
    const int quad = lane >> 4, col = lane & 15;
    const int bh   = blockIdx.x & 31;
    const int pair = blockIdx.x >> 5;         // 0..7
    const int b  = bh >> 4, h = bh & 15;
    const float nslope = -EXP2F(-0.5f * (float)(h + 1)) * LOG2E;

    const bf16* qp  = Q  + (size_t)bh * 2048 * 64;
    const bf16* kp  = Kg + (size_t)bh * 2048 * 64;
    const bf16* vtp = Vt + (size_t)bh * 64 * 2048;   // V^T: [64][2048]

    __shared__ alignas(16) bf16 Ps[8 * 16 * 136];
    bf16* Pw = Ps + w * (16 * 136);

    for (int pass = 0; pass < 2; ++pass) {
        const int qt = pass == 0 ? (15 - pair) : pair;
        const int q0 = qt * 128;

        bf16x8 qa[2];
#pragma unroll
        for (int ks = 0; ks < 2; ++ks)
            qa[ks] = *(const bf16x8*)(qp + (size_t)(q0 + w * 16 + col) * 64
                                      + ks * 32 + quad * 8);

        float mrow[4], lrow[4], bi[4];
        f32x4 of[4] = {};
        const int gi0 = q0 + w * 16 + quad * 4;
#pragma unroll
        for (int r = 0; r < 4; ++r) {
            mrow[r] = NEG_BIG; lrow[r] = 0.f;
            bi[r] = nslope * (float)(gi0 + r);
        }

        for (int kvt = 0; kvt <= qt; ++kvt) {
            const int kv0 = kvt * 128;

            // S = Q K^T — K fragments direct from global (L1-resident tile).
            // Per instr: 64 lanes x 16B = 16 fully-used 64B lines.
            f32x4 sc[8];
#pragma unroll
            for (int nj = 0; nj < 8; ++nj) {
                const bf16* kb = kp + (size_t)(kv0 + nj * 16 + col) * 64;
                bf16x8 k0f = *(const bf16x8*)(kb + quad * 8);
                bf16x8 k1f = *(const bf16x8*)(kb + 32 + quad * 8);
                f32x4 z = {};
                z = __builtin_amdgcn_mfma_f32_16x16x32_bf16(qa[0], k0f, z, 0, 0, 0);
                z = __builtin_amdgcn_mfma_f32_16x16x32_bf16(qa[1], k1f, z, 0, 0, 0);
                sc[nj] = z;
            }

            // softmax (exp2-domain, DPP reduces, hoisted ALiBi)
            const bool diag = (kvt == qt);
            float bj[8];
#pragma unroll
            for (int nj = 0; nj < 8; ++nj)
                bj[nj] = nslope * (float)(kv0 + nj * 16 + col);

#pragma unroll
            for (int r = 0; r < 4; ++r) {
#pragma unroll
                for (int nj = 0; nj < 8; ++nj)
                    sc[nj][r] += bi[r] - bj[nj];
                if (diag) {
                    const int gi = gi0 + r;
#pragma unroll
                    for (int nj = 0; nj < 8; ++nj)
                        if (kv0 + nj * 16 + col > gi) sc[nj][r] = NEG_BIG;
                }
                float mx = sc[0][r];
#pragma unroll
                for (int nj = 1; nj < 8; ++nj) mx = fmaxf(mx, sc[nj][r]);
                mx = red16_max(mx);
                const float mo = mrow[r];
                const float mn = fmaxf(mo, mx);
                const float alpha = EXP2F(mo - mn);
                float rs = 0.f;
#pragma unroll
                for (int nj = 0; nj < 8; ++nj) {
                    float p = EXP2F(sc[nj][r] - mn);
                    sc[nj][r] = p;
                    rs += p;
                }
                rs = red16_sum(rs);
                mrow[r] = mn;
                lrow[r] = lrow[r] * alpha + rs;
#pragma unroll
                for (int jd = 0; jd < 4; ++jd) of[jd][r] *= alpha;
            }

            // P: C/D -> A-operand layout via private per-wave LDS region
            // (wave-private: no barrier; compiler inserts the lgkmcnt)
#pragma unroll
            for (int nj = 0; nj < 8; ++nj)
#pragma unroll
                for (int r = 0; r < 4; ++r)
                    Pw[(quad * 4 + r) * 136 + nj * 16 + col] = (bf16)sc[nj][r];

            // O += P V — V^T fragments direct from global (L1-resident tile);
            // loads are softmax-independent so the scheduler hoists them.
#pragma unroll
            for (int kk = 0; kk < 4; ++kk) {
                bf16x8 pa = *(const bf16x8*)(Pw + col * 136 + kk * 32 + quad * 8);
#pragma unroll
                for (int jd = 0; jd < 4; ++jd) {
                    const int rd = jd * 16 + col;
                    bf16x8 vbf = *(const bf16x8*)(vtp + (size_t)rd * 2048 + kv0 + kk * 32 + quad * 8);
                    of[jd] = __builtin_amdgcn_mfma_f32_16x16x32_bf16(pa, vbf, of[jd], 0, 0, 0);
                }
            }
        }

        // normalize + write this q-tile's attn output (bf16) to [B,S,E]
#pragma unroll
        for (int r = 0; r < 4; ++r) {
            const int s = q0 + w * 16 + quad * 4 + r;
            const float inv_l = 1.f / lrow[r];
#pragma unroll
            for (int jd = 0; jd < 4; ++jd) {
                const int e = h * 64 + jd * 16 + col;
                O[((size_t)(b * 2048 + s)) * 1024 + e] = (bf16)(of[jd][r] * inv_l);
            }
        }
    }
}

// ---------------------------------------------------------------------------
// Output projection (R7-proven): A bf16 via stage16; Wo f32 via cvt8.
// ---------------------------------------------------------------------------
__global__ __launch_bounds__(256) void out_gemm(
    const bf16* __restrict__ A, const float* __restrict__ W,
    const float* __restrict__ bias, float* __restrict__ out)
{
    __shared__ alignas(16) bf16 As[128 * 32];
    __shared__ alignas(16) bf16 Bs[128 * 32];

    const int t    = threadIdx.x;
    const int lane = t & 63, w = t >> 6;
    const int quad = lane >> 4, col = lane & 15;
    const int n0 = blockIdx.x * 128;
    const int m0 = blockIdx.y * 128;
    const int K  = 1024;
    const int wm = (w >> 1) * 64, wn = (w & 1) * 64;
    const int r0 = t >> 2, c8 = (t & 3) * 8;
    f32x4 acc[4][4] = {};

    for (int k0 = 0; k0 < K; k0 += 32) {
        bf16x8 bx0 = cvt8(W + (size_t)(n0 + r0)      * K + k0 + c8);
        bf16x8 bx1 = cvt8(W + (size_t)(n0 + 64 + r0) * K + k0 + c8);
        __syncthreads();
#pragma unroll
        for (int i = 0; i < 2; ++i) {
            int c = i * 256 + t;
            stage16(A + (size_t)(m0 + (c >> 2)) * K + k0 + (c & 3) * 8,
                    As + (i * 256 + w * 64) * 8);
        }
        *(bf16x8*)(Bs + r0 * 32 + c8)        = bx0;
        *(bf16x8*)(Bs + (64 + r0) * 32 + c8) = bx1;
        __syncthreads();

        bf16x8 a[4], b[4];
#pragma unroll
        for (int i = 0; i < 4; ++i)
            a[i] = *(const bf16x8*)(As + (wm + i * 16 + col) * 32 + quad * 8);
#pragma unroll
        for (int j = 0; j < 4; ++j)
            b[j] = *(const bf16x8*)(Bs + (wn + j * 16 + col) * 32 + quad * 8);
#pragma unroll
        for (int i = 0; i < 4; ++i)
#pragma unroll
            for (int j = 0; j < 4; ++j)
                acc[i][j] = __builtin_amdgcn_mfma_f32_16x16x32_bf16(a[i], b[j], acc[i][j], 0, 0, 0);
    }

#pragma unroll
    for (int i = 0; i < 4; ++i) {
        const int mbase = m0 + wm + i * 16 + quad * 4;
#pragma unroll
        for (int j = 0; j < 4; ++j) {
            const int n = n0 + wn + j * 16 + col;
            const float bb = bias[n];
#pragma unroll
            for (int r = 0; r < 4; ++r)
                out[(size_t)(mbase + r) * 1024 + n] = acc[i][j][r] + bb;
        }
    }
}

extern "C" void kernel_launch(void* const* d_in, const int* in_sizes, int n_in,
                              void* d_out, int out_size, void* d_ws, size_t ws_size,
                              hipStream_t stream) {
    const float* x  = (const float*)d_in[0];
    const float* Wq = (const float*)d_in[1];
    const float* bq = (const float*)d_in[2];
    const float* Wk = (const float*)d_in[3];
    const float* bk = (const float*)d_in[4];
    const float* Wv = (const float*)d_in[5];
    const float* bv = (const float*)d_in[6];
    const float* Wo = (const float*)d_in[7];
    const float* bo = (const float*)d_in[8];
    float* out = (float*)d_out;

    // ws (32 MB, proven): [xb | q | k | v^T] bf16; attn output aliases xb.
    bf16* xb  = (bf16*)d_ws;
    bf16* qws = xb  + 4194304;
    bf16* kws = qws + 4194304;
    bf16* vws = kws + 4194304;
    bf16* aws = xb;

    // d_out scratch: bf16 Wq|Wk|Wv (6 MB); dead before out_gemm writes.
    bf16* wb = (bf16*)d_out;

    conv_all<<<dim3(3584), 256, 0, stream>>>(x, Wq, Wk, Wv, xb, wb);
    qkv_gemm<<<dim3(24, 32), 256, 0, stream>>>(xb, wb, bq, bk, bv, qws, kws, vws);
    attn_kernel<<<dim3(256), 512, 0, stream>>>(qws, kws, vws, aws);
    out_gemm<<<dim3(8, 32), 256, 0, stream>>>(aws, Wo, bo, out);
}

// Round 5
// 209.953 us; speedup vs baseline: 1.3992x; 1.3992x over previous
//
#include <hip/hip_runtime.h>
#include <hip/hip_bf16.h>

typedef __bf16 bf16;
typedef __bf16 bf16x4 __attribute__((ext_vector_type(4)));
typedef __bf16 bf16x8 __attribute__((ext_vector_type(8)));
typedef float  f32x4  __attribute__((ext_vector_type(4)));

#define NEG_BIG (-1e30f)
#define LOG2E 1.44269504088896340736f

#define AS1(p) ((const __attribute__((address_space(1))) void*)(p))
#define AS3(p) ((__attribute__((address_space(3))) void*)(p))

// async global->LDS, 16B/lane; dest = wave-uniform base + lane*16 (m104/m108)
__device__ __forceinline__ void stage16(const void* g, void* lds_uniform_base) {
    __builtin_amdgcn_global_load_lds(AS1(g), AS3(lds_uniform_base), 16, 0, 0);
}

__device__ __forceinline__ bf16x8 cvt8(const float* __restrict__ p) {
    bf16x8 r;
#pragma unroll
    for (int i = 0; i < 8; ++i) r[i] = (bf16)p[i];
    return r;
}

// lane ^ 16 exchange via ds_swizzle BitMode (xor=16, and=0x1F -> 0x401F)
__device__ __forceinline__ float swz_x16(float x) {
    return __builtin_bit_cast(float,
        __builtin_amdgcn_ds_swizzle(__builtin_bit_cast(int, x), 0x401F));
}

#if __has_builtin(__builtin_amdgcn_exp2f)
#define EXP2F(x) __builtin_amdgcn_exp2f(x)
#else
#define EXP2F(x) exp2f(x)
#endif

// ---------------------------------------------------------------------------
// f32->bf16: x -> xb (ws), Wq/Wk/Wv -> wb (d_out scratch). (R7-proven.)
// ---------------------------------------------------------------------------
__global__ __launch_bounds__(256) void conv_all(
    const float* __restrict__ x,  const float* __restrict__ wq,
    const float* __restrict__ wk, const float* __restrict__ wv,
    bf16* __restrict__ xb, bf16* __restrict__ wb)
{
    const int blk = blockIdx.x;
    const float* src; bf16* dst; size_t off;
    if (blk < 2048)      { src = x;  dst = xb;           off = (size_t)blk * 2048; }
    else if (blk < 2560) { src = wq; dst = wb;           off = (size_t)(blk - 2048) * 2048; }
    else if (blk < 3072) { src = wk; dst = wb + 1048576; off = (size_t)(blk - 2560) * 2048; }
    else                 { src = wv; dst = wb + 2097152; off = (size_t)(blk - 3072) * 2048; }
    const size_t i = off + (size_t)threadIdx.x * 8;
    *(bf16x8*)(dst + i) = cvt8(src + i);
}

// ---------------------------------------------------------------------------
// Fused QKV projection, all-bf16 (R7-proven core). y = xb @ Wb.T + b.
// Q is scaled by 0.125*log2e (exp2-domain softmax). V is written TRANSPOSED:
// V^T[bh][64][2048] so attn can stage it with global_load_lds (no transpose).
// ---------------------------------------------------------------------------
__global__ __launch_bounds__(256) void qkv_gemm(
    const bf16* __restrict__ Xb, const bf16* __restrict__ Wb,
    const float* __restrict__ bq, const float* __restrict__ bk, const float* __restrict__ bv,
    bf16* __restrict__ qo, bf16* __restrict__ ko, bf16* __restrict__ vo)
{
    __shared__ alignas(16) bf16 As[128 * 32];
    __shared__ alignas(16) bf16 Bs[128 * 32];

    const int t    = threadIdx.x;
    const int lane = t & 63, w = t >> 6;
    const int quad = lane >> 4, col = lane & 15;
    const int nt = blockIdx.x;            // 0..23
    const int mt = blockIdx.y;            // 0..31
    const int region = nt >> 3;           // 0=q 1=k 2=v
    const int n0 = (nt & 7) * 128;
    const int m0 = mt * 128;
    const int K  = 1024;

    const bf16*  W    = Wb + (size_t)region * 1048576;
    const float* bias = region == 0 ? bq : (region == 1 ? bk : bv);

    const int wm = (w >> 1) * 64, wn = (w & 1) * 64;
    f32x4 acc[4][4] = {};

    for (int k0 = 0; k0 < K; k0 += 32) {
        __syncthreads();
#pragma unroll
        for (int i = 0; i < 2; ++i) {
            int c = i * 256 + t;
            stage16(Xb + (size_t)(m0 + (c >> 2)) * K + k0 + (c & 3) * 8,
                    As + (i * 256 + w * 64) * 8);
        }
#pragma unroll
        for (int i = 0; i < 2; ++i) {
            int c = i * 256 + t;
            stage16(W + (size_t)(n0 + (c >> 2)) * K + k0 + (c & 3) * 8,
                    Bs + (i * 256 + w * 64) * 8);
        }
        __syncthreads();

        bf16x8 a[4], b[4];
#pragma unroll
        for (int i = 0; i < 4; ++i)
            a[i] = *(const bf16x8*)(As + (wm + i * 16 + col) * 32 + quad * 8);
#pragma unroll
        for (int j = 0; j < 4; ++j)
            b[j] = *(const bf16x8*)(Bs + (wn + j * 16 + col) * 32 + quad * 8);
#pragma unroll
        for (int i = 0; i < 4; ++i)
#pragma unroll
            for (int j = 0; j < 4; ++j)
                acc[i][j] = __builtin_amdgcn_mfma_f32_16x16x32_bf16(a[i], b[j], acc[i][j], 0, 0, 0);
    }

    if (region == 2) {
        // V^T epilogue: rows d = n&63, cols s (contiguous in r) -> packed 8B stores
#pragma unroll
        for (int i = 0; i < 4; ++i) {
            const int mbase = m0 + wm + i * 16 + quad * 4;
            const int b_ = mbase >> 11, s = mbase & 2047;
#pragma unroll
            for (int j = 0; j < 4; ++j) {
                const int n = n0 + wn + j * 16 + col;
                const float bb = bias[n];
                const int h = n >> 6, d = n & 63;
                bf16x4 pk;
#pragma unroll
                for (int r = 0; r < 4; ++r) pk[r] = (bf16)(acc[i][j][r] + bb);
                *(bf16x4*)(vo + ((size_t)(b_ * 16 + h) * 64 + d) * 2048 + s) = pk;
            }
        }
    } else {
        bf16* out = region == 0 ? qo : ko;
        const float scale = region == 0 ? (0.125f * LOG2E) : 1.0f;
#pragma unroll
        for (int i = 0; i < 4; ++i) {
            const int mbase = m0 + wm + i * 16 + quad * 4;
#pragma unroll
            for (int j = 0; j < 4; ++j) {
                const int n = n0 + wn + j * 16 + col;
                const float bb = bias[n];
                const int h = n >> 6, d = n & 63;
#pragma unroll
                for (int r = 0; r < 4; ++r) {
                    const int m  = mbase + r;
                    const int b_ = m >> 11, s = m & 2047;
                    out[(((size_t)(b_ * 16 + h)) * 2048 + s) * 64 + d] =
                        (bf16)((acc[i][j][r] + bb) * scale);
                }
            }
        }
    }
}

// ---------------------------------------------------------------------------
// Flash attention — R3 staged/dbuf structure, but each wave now owns
// 32 q-rows x one 64-kv HALF of every tile (wave pairs split kv):
//   wave w: qs=(w>>1)*32, kvh=(w&1)*64. Per-wave LDS reads drop 36KB->20KB
//   (DS pipe was the R3 bottleneck; per-CU DS 288KB->168KB per step).
// QK^T is operand-SWAPPED: sc = mfma(K,Q) = P^T, so
//   - P-writes are 8x ds_write_b64 (was 32x b16),
//   - m/l are per-lane scalars (q = col), alpha rescale broadcast-free,
//   - PV computes O^T = mfma(V^T, P^T); final store packs bf16x4.
// Softmax row-reduce = in-lane(16) + lane^16 (ds_swizzle) + lane^32 (shfl).
// Wave pairs merge kv-partials (m,l,O) once per q-tile via Kbuf (idle then).
// LDS: K dbuf 32K + V dbuf 32K + P 8x32x72 bf16 = 36864 -> 102400 B.
// ---------------------------------------------------------------------------
__global__ __launch_bounds__(512, 2) void attn_kernel(
    const bf16* __restrict__ Q, const bf16* __restrict__ Kg,
    const bf16* __restrict__ Vt, bf16* __restrict__ O)
{
    const int t    = threadIdx.x;
    const int lane = t & 63, w = t >> 6;      // w = 0..7
    const int quad = lane >> 4, col = lane & 15;
    const int bh   = blockIdx.x & 31;
    const int pair = blockIdx.x >> 5;         // 0..7
    const int b  = bh >> 4, h = bh & 15;
    const float nslope = -EXP2F(-0.5f * (float)(h + 1)) * LOG2E;

    const int qs  = (w >> 1) * 32;            // wave's 32 q-rows within the tile
    const int kvh = (w & 1) * 64;             // wave's kv half within each tile
    const int qo  = w & 1;                    // output half (qb) this wave finalizes

    const bf16* qp  = Q  + (size_t)bh * 2048 * 64;
    const bf16* kp  = Kg + (size_t)bh * 2048 * 64;
    const bf16* vtp = Vt + (size_t)bh * 64 * 2048;   // V^T: [64][2048]

    __shared__ alignas(16) bf16 Kbuf[2][128 * 64];
    __shared__ alignas(16) bf16 Vbuf[2][64 * 128];
    __shared__ alignas(16) bf16 Ps[8 * 32 * 72];
    bf16* Pw = Ps + w * (32 * 72);
    float* mergebuf = (float*)&Kbuf[0][0];    // 8192 floats; merge-time alias

    for (int pass = 0; pass < 2; ++pass) {
        const int qt = pass == 0 ? (15 - pair) : pair;
        const int q0 = qt * 128;

        // Q B-frags: qa[qb][kc] = Q[q0+qs+qb*16+col][kc*32+quad*8 ..]
        bf16x8 qa[2][2];
#pragma unroll
        for (int qb = 0; qb < 2; ++qb)
#pragma unroll
            for (int kc = 0; kc < 2; ++kc)
                qa[qb][kc] = *(const bf16x8*)(qp + (size_t)(q0 + qs + qb * 16 + col) * 64
                                              + kc * 32 + quad * 8);

        float m_[2], l_[2], bi[2];
        int   gl[2];
        f32x4 of[4][2] = {};                  // O^T: d=jd*16+quad*4+r, q=qs+qb*16+col
#pragma unroll
        for (int qb = 0; qb < 2; ++qb) {
            m_[qb] = NEG_BIG; l_[qb] = 0.f;
            gl[qb] = qs + qb * 16 + col;      // local q index in tile
            bi[qb] = nslope * (float)(q0 + gl[qb]);
        }

        // prologue: stage kv-tile 0 into buffer 0 (1024 16B-chunks each)
        {
#pragma unroll
            for (int i = 0; i < 2; ++i) {
                int c = i * 512 + t;
                int row = c >> 3, j8 = (c & 7) ^ (row & 7);
                stage16(kp + (size_t)row * 64 + j8 * 8, Kbuf[0] + (i * 512 + w * 64) * 8);
            }
#pragma unroll
            for (int i = 0; i < 2; ++i) {
                int c = i * 512 + t;
                int d = c >> 4, j8 = (c & 15) ^ (d & 7);
                stage16(vtp + (size_t)d * 2048 + j8 * 8, Vbuf[0] + (i * 512 + w * 64) * 8);
            }
        }
        __syncthreads();

        for (int kvt = 0; kvt <= qt; ++kvt) {
            const int kv0 = kvt * 128;
            const bf16* Kb = Kbuf[kvt & 1];
            const bf16* Vb = Vbuf[kvt & 1];

            // prefetch next tile into the other buffer (async; drained by the
            // end-of-iteration barrier)
            if (kvt < qt) {
                bf16* Kn = Kbuf[(kvt & 1) ^ 1];
                bf16* Vn = Vbuf[(kvt & 1) ^ 1];
                const int nv0 = kv0 + 128;
#pragma unroll
                for (int i = 0; i < 2; ++i) {
                    int c = i * 512 + t;
                    int row = c >> 3, j8 = (c & 7) ^ (row & 7);
                    stage16(kp + (size_t)(nv0 + row) * 64 + j8 * 8, Kn + (i * 512 + w * 64) * 8);
                }
#pragma unroll
                for (int i = 0; i < 2; ++i) {
                    int c = i * 512 + t;
                    int d = c >> 4, j8 = (c & 15) ^ (d & 7);
                    stage16(vtp + (size_t)d * 2048 + nv0 + j8 * 8, Vn + (i * 512 + w * 64) * 8);
                }
            }

            // S^T = K Q^T (swapped): sc[nj][qb] holds P^T[kv][q]
            //   kv = kvh + nj*16 + quad*4 + r, q = qs + qb*16 + col
            f32x4 sc[4][2];
#pragma unroll
            for (int nj = 0; nj < 4; ++nj) {
                const int row = kvh + nj * 16 + col;
                const bf16* kb = Kb + row * 64;
                const int rx = row & 7;
                bf16x8 kA0 = *(const bf16x8*)(kb + ((quad) ^ rx) * 8);
                bf16x8 kA1 = *(const bf16x8*)(kb + ((quad + 4) ^ rx) * 8);
#pragma unroll
                for (int qb = 0; qb < 2; ++qb) {
                    f32x4 z = {};
                    z = __builtin_amdgcn_mfma_f32_16x16x32_bf16(kA0, qa[qb][0], z, 0, 0, 0);
                    z = __builtin_amdgcn_mfma_f32_16x16x32_bf16(kA1, qa[qb][1], z, 0, 0, 0);
                    sc[nj][qb] = z;
                }
            }

            // softmax (exp2-domain); per-lane scalar m/l per qb
            const bool diag = (kvt == qt);
            const float bj0 = nslope * (float)(kv0 + kvh + quad * 4);
            const int   kvb = kvh + quad * 4;
#pragma unroll
            for (int qb = 0; qb < 2; ++qb) {
                float mx = NEG_BIG;
#pragma unroll
                for (int nj = 0; nj < 4; ++nj)
#pragma unroll
                    for (int r = 0; r < 4; ++r) {
                        float v = sc[nj][qb][r] + (bi[qb] - (bj0 + nslope * (float)(nj * 16 + r)));
                        if (diag && (kvb + nj * 16 + r > gl[qb])) v = NEG_BIG;
                        sc[nj][qb][r] = v;
                        mx = fmaxf(mx, v);
                    }
                mx = fmaxf(mx, swz_x16(mx));
                mx = fmaxf(mx, __shfl_xor(mx, 32, 64));
                const float mo = m_[qb];
                const float mn = fmaxf(mo, mx);
                const float alpha = EXP2F(mo - mn);
                float rs = 0.f;
#pragma unroll
                for (int nj = 0; nj < 4; ++nj)
#pragma unroll
                    for (int r = 0; r < 4; ++r) {
                        float p = EXP2F(sc[nj][qb][r] - mn);
                        sc[nj][qb][r] = p;
                        rs += p;
                    }
                rs += swz_x16(rs);
                rs += __shfl_xor(rs, 32, 64);
                m_[qb] = mn;
                l_[qb] = l_[qb] * alpha + rs;
#pragma unroll
                for (int jd = 0; jd < 4; ++jd) of[jd][qb] *= alpha;
            }

            // P^T -> LDS, packed b64 (4 consecutive kv per lane)
#pragma unroll
            for (int qb = 0; qb < 2; ++qb)
#pragma unroll
                for (int nj = 0; nj < 4; ++nj) {
                    bf16x4 pk;
#pragma unroll
                    for (int r = 0; r < 4; ++r) pk[r] = (bf16)sc[nj][qb][r];
                    *(bf16x4*)(Pw + (qb * 16 + col) * 72 + nj * 16 + quad * 4) = pk;
                }

            // O^T += V^T P^T over this wave's kv half
#pragma unroll
            for (int kk = 0; kk < 2; ++kk) {
                const int vc = (w & 1) * 8 + kk * 4 + quad;
                bf16x8 pB0 = *(const bf16x8*)(Pw + (col)      * 72 + kk * 32 + quad * 8);
                bf16x8 pB1 = *(const bf16x8*)(Pw + (16 + col) * 72 + kk * 32 + quad * 8);
#pragma unroll
                for (int jd = 0; jd < 4; ++jd) {
                    const int rd = jd * 16 + col;
                    bf16x8 vA = *(const bf16x8*)(Vb + rd * 128 + ((vc ^ (rd & 7)) * 8));
                    of[jd][0] = __builtin_amdgcn_mfma_f32_16x16x32_bf16(vA, pB0, of[jd][0], 0, 0, 0);
                    of[jd][1] = __builtin_amdgcn_mfma_f32_16x16x32_bf16(vA, pB1, of[jd][1], 0, 0, 0);
                }
            }

            // ONE barrier: Kb/Vb reads done + prefetch drained for next iter
            __syncthreads();
        }

        // ---- merge wave-pair kv-partials (m,l,O), write output ----
        // Each wave writes the frags its partner finalizes (qb = qo^1) into
        // Kbuf (idle now), m/l into its own P region; partner reads them.
        {
            float* mb = mergebuf + w * 1024;
#pragma unroll
            for (int jd = 0; jd < 4; ++jd)
                *(f32x4*)(mb + jd * 256 + lane * 4) = of[jd][qo ^ 1];
            float* mlw = (float*)Pw;
            mlw[lane * 2]     = m_[qo ^ 1];
            mlw[lane * 2 + 1] = l_[qo ^ 1];
            __syncthreads();

            const float* mbp = mergebuf + (w ^ 1) * 1024;
            const float* mlp = (const float*)(Ps + (w ^ 1) * (32 * 72));
            const float m1 = mlp[lane * 2], l1 = mlp[lane * 2 + 1];
            const float m0 = m_[qo], l0 = l_[qo];
            const float mt = fmaxf(m0, m1);
            const float a0 = EXP2F(m0 - mt), a1 = EXP2F(m1 - mt);
            const float inv = 1.f / (l0 * a0 + l1 * a1);
            const int s = q0 + qs + qo * 16 + col;
#pragma unroll
            for (int jd = 0; jd < 4; ++jd) {
                f32x4 o1 = *(const f32x4*)(mbp + jd * 256 + lane * 4);
                bf16x4 pk;
#pragma unroll
                for (int r = 0; r < 4; ++r)
                    pk[r] = (bf16)((of[jd][qo][r] * a0 + o1[r] * a1) * inv);
                *(bf16x4*)(O + ((size_t)(b * 2048 + s)) * 1024 + h * 64 + jd * 16 + quad * 4) = pk;
            }
            __syncthreads();   // protect merge buffers from next pass's staging
        }
    }
}

// ---------------------------------------------------------------------------
// Output projection (R7-proven): A bf16 via stage16; Wo f32 via cvt8.
// ---------------------------------------------------------------------------
__global__ __launch_bounds__(256) void out_gemm(
    const bf16* __restrict__ A, const float* __restrict__ W,
    const float* __restrict__ bias, float* __restrict__ out)
{
    __shared__ alignas(16) bf16 As[128 * 32];
    __shared__ alignas(16) bf16 Bs[128 * 32];

    const int t    = threadIdx.x;
    const int lane = t & 63, w = t >> 6;
    const int quad = lane >> 4, col = lane & 15;
    const int n0 = blockIdx.x * 128;
    const int m0 = blockIdx.y * 128;
    const int K  = 1024;
    const int wm = (w >> 1) * 64, wn = (w & 1) * 64;
    const int r0 = t >> 2, c8 = (t & 3) * 8;
    f32x4 acc[4][4] = {};

    for (int k0 = 0; k0 < K; k0 += 32) {
        bf16x8 bx0 = cvt8(W + (size_t)(n0 + r0)      * K + k0 + c8);
        bf16x8 bx1 = cvt8(W + (size_t)(n0 + 64 + r0) * K + k0 + c8);
        __syncthreads();
#pragma unroll
        for (int i = 0; i < 2; ++i) {
            int c = i * 256 + t;
            stage16(A + (size_t)(m0 + (c >> 2)) * K + k0 + (c & 3) * 8,
                    As + (i * 256 + w * 64) * 8);
        }
        *(bf16x8*)(Bs + r0 * 32 + c8)        = bx0;
        *(bf16x8*)(Bs + (64 + r0) * 32 + c8) = bx1;
        __syncthreads();

        bf16x8 a[4], b[4];
#pragma unroll
        for (int i = 0; i < 4; ++i)
            a[i] = *(const bf16x8*)(As + (wm + i * 16 + col) * 32 + quad * 8);
#pragma unroll
        for (int j = 0; j < 4; ++j)
            b[j] = *(const bf16x8*)(Bs + (wn + j * 16 + col) * 32 + quad * 8);
#pragma unroll
        for (int i = 0; i < 4; ++i)
#pragma unroll
            for (int j = 0; j < 4; ++j)
                acc[i][j] = __builtin_amdgcn_mfma_f32_16x16x32_bf16(a[i], b[j], acc[i][j], 0, 0, 0);
    }

#pragma unroll
    for (int i = 0; i < 4; ++i) {
        const int mbase = m0 + wm + i * 16 + quad * 4;
#pragma unroll
        for (int j = 0; j < 4; ++j) {
            const int n = n0 + wn + j * 16 + col;
            const float bb = bias[n];
#pragma unroll
            for (int r = 0; r < 4; ++r)
                out[(size_t)(mbase + r) * 1024 + n] = acc[i][j][r] + bb;
        }
    }
}

extern "C" void kernel_launch(void* const* d_in, const int* in_sizes, int n_in,
                              void* d_out, int out_size, void* d_ws, size_t ws_size,
                              hipStream_t stream) {
    const float* x  = (const float*)d_in[0];
    const float* Wq = (const float*)d_in[1];
    const float* bq = (const float*)d_in[2];
    const float* Wk = (const float*)d_in[3];
    const float* bk = (const float*)d_in[4];
    const float* Wv = (const float*)d_in[5];
    const float* bv = (const float*)d_in[6];
    const float* Wo = (const float*)d_in[7];
    const float* bo = (const float*)d_in[8];
    float* out = (float*)d_out;

    // ws (32 MB, proven): [xb | q | k | v^T] bf16; attn output aliases xb.
    bf16* xb  = (bf16*)d_ws;
    bf16* qws = xb  + 4194304;
    bf16* kws = qws + 4194304;
    bf16* vws = kws + 4194304;
    bf16* aws = xb;

    // d_out scratch: bf16 Wq|Wk|Wv (6 MB); dead before out_gemm writes.
    bf16* wb = (bf16*)d_out;

    conv_all<<<dim3(3584), 256, 0, stream>>>(x, Wq, Wk, Wv, xb, wb);
    qkv_gemm<<<dim3(24, 32), 256, 0, stream>>>(xb, wb, bq, bk, bv, qws, kws, vws);
    attn_kernel<<<dim3(256), 512, 0, stream>>>(qws, kws, vws, aws);
    out_gemm<<<dim3(8, 32), 256, 0, stream>>>(aws, Wo, bo, out);
}

// Round 7
// 204.097 us; speedup vs baseline: 1.4393x; 1.0287x over previous
//
#include <hip/hip_runtime.h>
#include <hip/hip_bf16.h>

typedef __bf16 bf16;
typedef __bf16 bf16x4 __attribute__((ext_vector_type(4)));
typedef __bf16 bf16x8 __attribute__((ext_vector_type(8)));
typedef float  f32x4  __attribute__((ext_vector_type(4)));

#define NEG_BIG (-1e30f)
#define LOG2E 1.44269504088896340736f

#define AS1(p) ((const __attribute__((address_space(1))) void*)(p))
#define AS3(p) ((__attribute__((address_space(3))) void*)(p))

// async global->LDS, 16B/lane; dest = wave-uniform base + lane*16 (m104/m108)
__device__ __forceinline__ void stage16(const void* g, void* lds_uniform_base) {
    __builtin_amdgcn_global_load_lds(AS1(g), AS3(lds_uniform_base), 16, 0, 0);
}

__device__ __forceinline__ bf16x8 cvt8(const float* __restrict__ p) {
    bf16x8 r;
#pragma unroll
    for (int i = 0; i < 8; ++i) r[i] = (bf16)p[i];
    return r;
}

// ---- DPP butterfly reduce over 16 consecutive lanes (pure VALU, no LDS) ----
template <int CTRL>
__device__ __forceinline__ float dpp_max_step(float x) {
    int v = __builtin_bit_cast(int, x);
    int s = __builtin_amdgcn_update_dpp(v, v, CTRL, 0xF, 0xF, true);
    return fmaxf(x, __builtin_bit_cast(float, s));
}
template <int CTRL>
__device__ __forceinline__ float dpp_add_step(float x) {
    int v = __builtin_bit_cast(int, x);
    int s = __builtin_amdgcn_update_dpp(v, v, CTRL, 0xF, 0xF, true);
    return x + __builtin_bit_cast(float, s);
}
__device__ __forceinline__ float red16_max(float x) {
    x = dpp_max_step<0xB1>(x);
    x = dpp_max_step<0x4E>(x);
    x = dpp_max_step<0x141>(x);
    x = dpp_max_step<0x140>(x);
    return x;
}
__device__ __forceinline__ float red16_sum(float x) {
    x = dpp_add_step<0xB1>(x);
    x = dpp_add_step<0x4E>(x);
    x = dpp_add_step<0x141>(x);
    x = dpp_add_step<0x140>(x);
    return x;
}

#if __has_builtin(__builtin_amdgcn_exp2f)
#define EXP2F(x) __builtin_amdgcn_exp2f(x)
#else
#define EXP2F(x) exp2f(x)
#endif

// ---------------------------------------------------------------------------
// f32->bf16: x -> xb (ws), Wq/Wk/Wv -> wb (d_out scratch). (R7-proven.)
// ---------------------------------------------------------------------------
__global__ __launch_bounds__(256) void conv_all(
    const float* __restrict__ x,  const float* __restrict__ wq,
    const float* __restrict__ wk, const float* __restrict__ wv,
    bf16* __restrict__ xb, bf16* __restrict__ wb)
{
    const int blk = blockIdx.x;
    const float* src; bf16* dst; size_t off;
    if (blk < 2048)      { src = x;  dst = xb;           off = (size_t)blk * 2048; }
    else if (blk < 2560) { src = wq; dst = wb;           off = (size_t)(blk - 2048) * 2048; }
    else if (blk < 3072) { src = wk; dst = wb + 1048576; off = (size_t)(blk - 2560) * 2048; }
    else                 { src = wv; dst = wb + 2097152; off = (size_t)(blk - 3072) * 2048; }
    const size_t i = off + (size_t)threadIdx.x * 8;
    *(bf16x8*)(dst + i) = cvt8(src + i);
}

// ---------------------------------------------------------------------------
// Fused QKV projection, all-bf16 (R7-proven core). y = xb @ Wb.T + b.
// Q is scaled by 0.125*log2e (exp2-domain softmax). V is written TRANSPOSED:
// V^T[bh][64][2048] so attn can stage it with global_load_lds (no transpose).
// ---------------------------------------------------------------------------
__global__ __launch_bounds__(256) void qkv_gemm(
    const bf16* __restrict__ Xb, const bf16* __restrict__ Wb,
    const float* __restrict__ bq, const float* __restrict__ bk, const float* __restrict__ bv,
    bf16* __restrict__ qo, bf16* __restrict__ ko, bf16* __restrict__ vo)
{
    __shared__ alignas(16) bf16 As[128 * 32];
    __shared__ alignas(16) bf16 Bs[128 * 32];

    const int t    = threadIdx.x;
    const int lane = t & 63, w = t >> 6;
    const int quad = lane >> 4, col = lane & 15;
    const int nt = blockIdx.x;            // 0..23
    const int mt = blockIdx.y;            // 0..31
    const int region = nt >> 3;           // 0=q 1=k 2=v
    const int n0 = (nt & 7) * 128;
    const int m0 = mt * 128;
    const int K  = 1024;

    const bf16*  W    = Wb + (size_t)region * 1048576;
    const float* bias = region == 0 ? bq : (region == 1 ? bk : bv);

    const int wm = (w >> 1) * 64, wn = (w & 1) * 64;
    f32x4 acc[4][4] = {};

    for (int k0 = 0; k0 < K; k0 += 32) {
        __syncthreads();
#pragma unroll
        for (int i = 0; i < 2; ++i) {
            int c = i * 256 + t;
            stage16(Xb + (size_t)(m0 + (c >> 2)) * K + k0 + (c & 3) * 8,
                    As + (i * 256 + w * 64) * 8);
        }
#pragma unroll
        for (int i = 0; i < 2; ++i) {
            int c = i * 256 + t;
            stage16(W + (size_t)(n0 + (c >> 2)) * K + k0 + (c & 3) * 8,
                    Bs + (i * 256 + w * 64) * 8);
        }
        __syncthreads();

        bf16x8 a[4], b[4];
#pragma unroll
        for (int i = 0; i < 4; ++i)
            a[i] = *(const bf16x8*)(As + (wm + i * 16 + col) * 32 + quad * 8);
#pragma unroll
        for (int j = 0; j < 4; ++j)
            b[j] = *(const bf16x8*)(Bs + (wn + j * 16 + col) * 32 + quad * 8);
#pragma unroll
        for (int i = 0; i < 4; ++i)
#pragma unroll
            for (int j = 0; j < 4; ++j)
                acc[i][j] = __builtin_amdgcn_mfma_f32_16x16x32_bf16(a[i], b[j], acc[i][j], 0, 0, 0);
    }

    if (region == 2) {
        // V^T epilogue: rows d = n&63, cols s (contiguous in r) -> packed 8B stores
#pragma unroll
        for (int i = 0; i < 4; ++i) {
            const int mbase = m0 + wm + i * 16 + quad * 4;
            const int b_ = mbase >> 11, s = mbase & 2047;
#pragma unroll
            for (int j = 0; j < 4; ++j) {
                const int n = n0 + wn + j * 16 + col;
                const float bb = bias[n];
                const int h = n >> 6, d = n & 63;
                bf16x4 pk;
#pragma unroll
                for (int r = 0; r < 4; ++r) pk[r] = (bf16)(acc[i][j][r] + bb);
                *(bf16x4*)(vo + ((size_t)(b_ * 16 + h) * 64 + d) * 2048 + s) = pk;
            }
        }
    } else {
        bf16* out = region == 0 ? qo : ko;
        const float scale = region == 0 ? (0.125f * LOG2E) : 1.0f;
#pragma unroll
        for (int i = 0; i < 4; ++i) {
            const int mbase = m0 + wm + i * 16 + quad * 4;
#pragma unroll
            for (int j = 0; j < 4; ++j) {
                const int n = n0 + wn + j * 16 + col;
                const float bb = bias[n];
                const int h = n >> 6, d = n & 63;
#pragma unroll
                for (int r = 0; r < 4; ++r) {
                    const int m  = mbase + r;
                    const int b_ = m >> 11, s = m & 2047;
                    out[(((size_t)(b_ * 16 + h)) * 2048 + s) * 64 + d] =
                        (bf16)((acc[i][j][r] + bb) * scale);
                }
            }
        }
    }
}

// ---------------------------------------------------------------------------
// Flash attention — R3 inner machinery, UNPAIRED 64-row q-tiles for 3x
// occupancy: grid = 32 tiles x 32 bh = 1024 blocks x 256 threads (4 waves
// x 16 q-rows). LDS 41984 B -> 3 blocks/CU resident = 3 waves/SIMD (R3: 2).
// Unequal block durations (qt+1 steps of 64 kv) are packed LPT-style:
// blockIdx maps longest-first (qt = 31 - z), short blocks backfill the tail
// — dispatch-order is a perf heuristic only, never correctness.
// Per step: stage16 K/V (XOR-swizzled both sides), dbuf, 1 barrier, DPP
// softmax reduces, exp2 domain, per-wave-private P (stride 72).
// ---------------------------------------------------------------------------
__global__ __launch_bounds__(256, 3) void attn_kernel(
    const bf16* __restrict__ Q, const bf16* __restrict__ Kg,
    const bf16* __restrict__ Vt, bf16* __restrict__ O)
{
    const int t    = threadIdx.x;
    const int lane = t & 63, w = t >> 6;      // w = 0..3
    const int quad = lane >> 4, col = lane & 15;
    const int bh   = blockIdx.x & 31;
    const int z    = blockIdx.x >> 5;         // 0..31
    const int qt   = 31 - z;                  // longest-first (LPT packing)
    const int b  = bh >> 4, h = bh & 15;
    const float nslope = -EXP2F(-0.5f * (float)(h + 1)) * LOG2E;

    const bf16* qp  = Q  + (size_t)bh * 2048 * 64;
    const bf16* kp  = Kg + (size_t)bh * 2048 * 64;
    const bf16* vtp = Vt + (size_t)bh * 64 * 2048;   // V^T: [64][2048]

    __shared__ alignas(16) bf16 Kbuf[2][64 * 64];
    __shared__ alignas(16) bf16 Vbuf[2][64 * 64];
    __shared__ alignas(16) bf16 Ps[4 * 16 * 72];
    bf16* Pw = Ps + w * (16 * 72);

    const int q0 = qt * 64;

    bf16x8 qa[2];
#pragma unroll
    for (int ks = 0; ks < 2; ++ks)
        qa[ks] = *(const bf16x8*)(qp + (size_t)(q0 + w * 16 + col) * 64
                                  + ks * 32 + quad * 8);

    float mrow[4], lrow[4], bi[4];
    f32x4 of[4] = {};
    const int gi0 = q0 + w * 16 + quad * 4;
#pragma unroll
    for (int r = 0; r < 4; ++r) {
        mrow[r] = NEG_BIG; lrow[r] = 0.f;
        bi[r] = nslope * (float)(gi0 + r);
    }

    // prologue: stage kv-tile 0 into buffer 0 (512 16B-chunks each)
    {
#pragma unroll
        for (int i = 0; i < 2; ++i) {
            int c = i * 256 + t;
            int row = c >> 3, j8 = (c & 7) ^ (row & 7);
            stage16(kp + (size_t)row * 64 + j8 * 8, Kbuf[0] + (i * 256 + w * 64) * 8);
        }
#pragma unroll
        for (int i = 0; i < 2; ++i) {
            int c = i * 256 + t;
            int d = c >> 3, j8 = (c & 7) ^ (d & 7);
            stage16(vtp + (size_t)d * 2048 + j8 * 8, Vbuf[0] + (i * 256 + w * 64) * 8);
        }
    }
    __syncthreads();

    for (int kvt = 0; kvt <= qt; ++kvt) {
        const int kv0 = kvt * 64;
        const bf16* Kb = Kbuf[kvt & 1];
        const bf16* Vb = Vbuf[kvt & 1];

        // prefetch next tile into the other buffer (async; drained by the
        // end-of-iteration barrier)
        if (kvt < qt) {
            bf16* Kn = Kbuf[(kvt & 1) ^ 1];
            bf16* Vn = Vbuf[(kvt & 1) ^ 1];
            const int nv0 = kv0 + 64;
#pragma unroll
            for (int i = 0; i < 2; ++i) {
                int c = i * 256 + t;
                int row = c >> 3, j8 = (c & 7) ^ (row & 7);
                stage16(kp + (size_t)(nv0 + row) * 64 + j8 * 8, Kn + (i * 256 + w * 64) * 8);
            }
#pragma unroll
            for (int i = 0; i < 2; ++i) {
                int c = i * 256 + t;
                int d = c >> 3, j8 = (c & 7) ^ (d & 7);
                stage16(vtp + (size_t)d * 2048 + nv0 + j8 * 8, Vn + (i * 256 + w * 64) * 8);
            }
        }

        // S = Q K^T  (swizzled K reads: chunk = (quad + 4*ks) ^ (row&7))
        f32x4 sc[4];
#pragma unroll
        for (int nj = 0; nj < 4; ++nj) {
            const int row = nj * 16 + col;
            const bf16* kb = Kb + row * 64;
            const int rx = row & 7;
            bf16x8 k0f = *(const bf16x8*)(kb + (quad ^ rx) * 8);
            bf16x8 k1f = *(const bf16x8*)(kb + ((quad + 4) ^ rx) * 8);
            f32x4 zz = {};
            zz = __builtin_amdgcn_mfma_f32_16x16x32_bf16(qa[0], k0f, zz, 0, 0, 0);
            zz = __builtin_amdgcn_mfma_f32_16x16x32_bf16(qa[1], k1f, zz, 0, 0, 0);
            sc[nj] = zz;
        }

        // softmax (exp2-domain, DPP reduces, hoisted ALiBi)
        const bool diag = (kvt == qt);
        float bj[4];
#pragma unroll
        for (int nj = 0; nj < 4; ++nj)
            bj[nj] = nslope * (float)(kv0 + nj * 16 + col);

#pragma unroll
        for (int r = 0; r < 4; ++r) {
#pragma unroll
            for (int nj = 0; nj < 4; ++nj)
                sc[nj][r] += bi[r] - bj[nj];
            if (diag) {
                const int gi = gi0 + r;
#pragma unroll
                for (int nj = 0; nj < 4; ++nj)
                    if (kv0 + nj * 16 + col > gi) sc[nj][r] = NEG_BIG;
            }
            float mx = sc[0][r];
#pragma unroll
            for (int nj = 1; nj < 4; ++nj) mx = fmaxf(mx, sc[nj][r]);
            mx = red16_max(mx);
            const float mo = mrow[r];
            const float mn = fmaxf(mo, mx);
            const float alpha = EXP2F(mo - mn);
            float rs = 0.f;
#pragma unroll
            for (int nj = 0; nj < 4; ++nj) {
                float p = EXP2F(sc[nj][r] - mn);
                sc[nj][r] = p;
                rs += p;
            }
            rs = red16_sum(rs);
            mrow[r] = mn;
            lrow[r] = lrow[r] * alpha + rs;
#pragma unroll
            for (int jd = 0; jd < 4; ++jd) of[jd][r] *= alpha;
        }

        // P: C/D -> A-operand layout via private per-wave LDS region
        // (wave-private: no barrier; compiler inserts the lgkmcnt)
#pragma unroll
        for (int nj = 0; nj < 4; ++nj)
#pragma unroll
            for (int r = 0; r < 4; ++r)
                Pw[(quad * 4 + r) * 72 + nj * 16 + col] = (bf16)sc[nj][r];

        // O += P V  (swizzled V reads: chunk = (kk*4+quad) ^ (d&7))
#pragma unroll
        for (int kk = 0; kk < 2; ++kk) {
            bf16x8 pa = *(const bf16x8*)(Pw + col * 72 + kk * 32 + quad * 8);
#pragma unroll
            for (int jd = 0; jd < 4; ++jd) {
                const int rd = jd * 16 + col;
                bf16x8 vbf = *(const bf16x8*)(Vb + rd * 64 + (((kk * 4 + quad) ^ (rd & 7)) * 8));
                of[jd] = __builtin_amdgcn_mfma_f32_16x16x32_bf16(pa, vbf, of[jd], 0, 0, 0);
            }
        }

        // ONE barrier: (a) everyone done reading Kb/Vb before next-iter
        // overwrite, (b) vmcnt drain -> prefetched tile visible next iter.
        __syncthreads();
    }

    // normalize + write this q-tile's attn output (bf16) to [B,S,E]
#pragma unroll
    for (int r = 0; r < 4; ++r) {
        const int s = q0 + w * 16 + quad * 4 + r;
        const float inv_l = 1.f / lrow[r];
#pragma unroll
        for (int jd = 0; jd < 4; ++jd) {
            const int e = h * 64 + jd * 16 + col;
            O[((size_t)(b * 2048 + s)) * 1024 + e] = (bf16)(of[jd][r] * inv_l);
        }
    }
}

// ---------------------------------------------------------------------------
// Output projection (R7-proven): A bf16 via stage16; Wo f32 via cvt8.
// ---------------------------------------------------------------------------
__global__ __launch_bounds__(256) void out_gemm(
    const bf16* __restrict__ A, const float* __restrict__ W,
    const float* __restrict__ bias, float* __restrict__ out)
{
    __shared__ alignas(16) bf16 As[128 * 32];
    __shared__ alignas(16) bf16 Bs[128 * 32];

    const int t    = threadIdx.x;
    const int lane = t & 63, w = t >> 6;
    const int quad = lane >> 4, col = lane & 15;
    const int n0 = blockIdx.x * 128;
    const int m0 = blockIdx.y * 128;
    const int K  = 1024;
    const int wm = (w >> 1) * 64, wn = (w & 1) * 64;
    const int r0 = t >> 2, c8 = (t & 3) * 8;
    f32x4 acc[4][4] = {};

    for (int k0 = 0; k0 < K; k0 += 32) {
        bf16x8 bx0 = cvt8(W + (size_t)(n0 + r0)      * K + k0 + c8);
        bf16x8 bx1 = cvt8(W + (size_t)(n0 + 64 + r0) * K + k0 + c8);
        __syncthreads();
#pragma unroll
        for (int i = 0; i < 2; ++i) {
            int c = i * 256 + t;
            stage16(A + (size_t)(m0 + (c >> 2)) * K + k0 + (c & 3) * 8,
                    As + (i * 256 + w * 64) * 8);
        }
        *(bf16x8*)(Bs + r0 * 32 + c8)        = bx0;
        *(bf16x8*)(Bs + (64 + r0) * 32 + c8) = bx1;
        __syncthreads();

        bf16x8 a[4], b[4];
#pragma unroll
        for (int i = 0; i < 4; ++i)
            a[i] = *(const bf16x8*)(As + (wm + i * 16 + col) * 32 + quad * 8);
#pragma unroll
        for (int j = 0; j < 4; ++j)
            b[j] = *(const bf16x8*)(Bs + (wn + j * 16 + col) * 32 + quad * 8);
#pragma unroll
        for (int i = 0; i < 4; ++i)
#pragma unroll
            for (int j = 0; j < 4; ++j)
                acc[i][j] = __builtin_amdgcn_mfma_f32_16x16x32_bf16(a[i], b[j], acc[i][j], 0, 0, 0);
    }

#pragma unroll
    for (int i = 0; i < 4; ++i) {
        const int mbase = m0 + wm + i * 16 + quad * 4;
#pragma unroll
        for (int j = 0; j < 4; ++j) {
            const int n = n0 + wn + j * 16 + col;
            const float bb = bias[n];
#pragma unroll
            for (int r = 0; r < 4; ++r)
                out[(size_t)(mbase + r) * 1024 + n] = acc[i][j][r] + bb;
        }
    }
}

extern "C" void kernel_launch(void* const* d_in, const int* in_sizes, int n_in,
                              void* d_out, int out_size, void* d_ws, size_t ws_size,
                              hipStream_t stream) {
    const float* x  = (const float*)d_in[0];
    const float* Wq = (const float*)d_in[1];
    const float* bq = (const float*)d_in[2];
    const float* Wk = (const float*)d_in[3];
    const float* bk = (const float*)d_in[4];
    const float* Wv = (const float*)d_in[5];
    const float* bv = (const float*)d_in[6];
    const float* Wo = (const float*)d_in[7];
    const float* bo = (const float*)d_in[8];
    float* out = (float*)d_out;

    // ws (32 MB, proven): [xb | q | k | v^T] bf16; attn output aliases xb.
    bf16* xb  = (bf16*)d_ws;
    bf16* qws = xb  + 4194304;
    bf16* kws = qws + 4194304;
    bf16* vws = kws + 4194304;
    bf16* aws = xb;

    // d_out scratch: bf16 Wq|Wk|Wv (6 MB); dead before out_gemm writes.
    bf16* wb = (bf16*)d_out;

    conv_all<<<dim3(3584), 256, 0, stream>>>(x, Wq, Wk, Wv, xb, wb);
    qkv_gemm<<<dim3(24, 32), 256, 0, stream>>>(xb, wb, bq, bk, bv, qws, kws, vws);
    attn_kernel<<<dim3(1024), 256, 0, stream>>>(qws, kws, vws, aws);
    out_gemm<<<dim3(8, 32), 256, 0, stream>>>(aws, Wo, bo, out);
}